// Round 11
// baseline (106.140 us; speedup 1.0000x reference)
//
#include <hip/hip_runtime.h>
#include <hip/hip_bf16.h>
#include <stdint.h>

typedef __attribute__((ext_vector_type(8))) __bf16 bf16x8;
typedef __attribute__((ext_vector_type(4))) float f32x4;
typedef __attribute__((ext_vector_type(8))) unsigned short u16x8;

__device__ __forceinline__ unsigned short f2bf(float f) {
    unsigned u = __builtin_bit_cast(unsigned, f);
    return (unsigned short)((u + 0x7fffu + ((u >> 16) & 1u)) >> 16);  // RNE
}

__device__ __forceinline__ void glds16(const void* g, void* l) {
    __builtin_amdgcn_global_load_lds(
        (const __attribute__((address_space(1))) unsigned int*)(uintptr_t)g,
        (__attribute__((address_space(3))) unsigned int*)l, 16, 0, 0);
}

#define VMCNT(n) asm volatile("s_waitcnt vmcnt(" #n ")" ::: "memory")
#define BAR()                                  \
    do {                                       \
        asm volatile("" ::: "memory");         \
        __builtin_amdgcn_s_barrier();          \
        asm volatile("" ::: "memory");         \
    } while (0)

#define MFMA16(a, b, c) __builtin_amdgcn_mfma_f32_16x16x32_bf16((a), (b), (c), 0, 0, 0)

// ---------------------------------------------------------------------------
// Kernel 1 (fused prep, VERIFIED R9): blocks [0,1024) build W; rest cvt x.
// ---------------------------------------------------------------------------
__global__ __launch_bounds__(256) void prep_fused(const float* __restrict__ factors,
                                                  const float* __restrict__ cores,
                                                  const float4* __restrict__ xin,
                                                  ushort4* __restrict__ xb,
                                                  unsigned short* __restrict__ Wt) {
    if (blockIdx.x >= 1024) {
        int i = (blockIdx.x - 1024) * 256 + threadIdx.x;
        float4 v = xin[i];
        ushort4 o;
        o.x = f2bf(v.x); o.y = f2bf(v.y); o.z = f2bf(v.z); o.w = f2bf(v.w);
        xb[i] = o;
        return;
    }
    __shared__ unsigned short As2[256 * 40];
    __shared__ unsigned short Bs2[64 * 40];
    __shared__ unsigned short lbuf[4 * 64 * 72];
    const int tid = threadIdx.x, lane = tid & 63, w = tid >> 6;
    const int bo = blockIdx.x >> 6, bn4 = (blockIdx.x >> 2) & 15, wn = blockIdx.x & 3;

    {   // As2 row tid: val = F0[a0,o0,r0]*F1[a1,o1,r1], k = b*4+q
        int o01 = bo * 4 + (tid >> 6), a01 = tid & 63;
        int o0 = o01 >> 3, o1 = o01 & 7, a0 = a01 >> 3, a1 = a01 & 7;
#pragma unroll
        for (int k = 0; k < 16; ++k) {
            int b = k >> 2, q = k & 3, r0 = q >> 1, r1 = q & 1;
            float v = factors[b*512 +   0 + a0*16 + o0*2 + r0]
                    * factors[b*512 + 128 + a1*16 + o1*2 + r1];
            As2[tid * 40 + k] = f2bf(v);
            As2[tid * 40 + 16 + k] = 0;
        }
    }
    {   // Bs2: 64 rows (a23) x 16 k; o23 fixed = bn4*4+wn
        int o23 = bn4 * 4 + wn, o2 = o23 >> 3, o3 = o23 & 7;
#pragma unroll
        for (int rep = 0; rep < 4; ++rep) {
            int task = rep * 256 + tid;
            int n = task >> 4, k = task & 15;
            int a2 = n >> 3, a3 = n & 7;
            int b = k >> 2, q = k & 3, r0 = q >> 1, r1 = q & 1;
            float s = 0.f;
#pragma unroll
            for (int r2 = 0; r2 < 2; ++r2)
#pragma unroll
                for (int r3 = 0; r3 < 2; ++r3)
                    s += factors[b*512 + 256 + a2*16 + o2*2 + r2]
                       * factors[b*512 + 384 + a3*16 + o3*2 + r3]
                       * cores[b*16 + r3*8 + r2*4 + r1*2 + r0];
            Bs2[n * 40 + k] = f2bf(s);
            Bs2[n * 40 + 16 + k] = 0;
        }
    }
    __syncthreads();

    const int fr = lane & 15, fh = lane >> 4;
    bf16x8 af[4], bf_[4];
#pragma unroll
    for (int mf = 0; mf < 4; ++mf)
        af[mf] = *(const bf16x8*)&As2[(w * 64 + mf * 16 + fr) * 40 + fh * 8];
#pragma unroll
    for (int nf = 0; nf < 4; ++nf)
        bf_[nf] = *(const bf16x8*)&Bs2[(nf * 16 + fr) * 40 + fh * 8];
    f32x4 acc[4][4] = {};
#pragma unroll
    for (int mf = 0; mf < 4; ++mf)
#pragma unroll
        for (int nf = 0; nf < 4; ++nf)
            acc[mf][nf] = MFMA16(af[mf], bf_[nf], acc[mf][nf]);
#pragma unroll
    for (int mf = 0; mf < 4; ++mf)
#pragma unroll
        for (int nf = 0; nf < 4; ++nf)
#pragma unroll
            for (int j = 0; j < 4; ++j)
                lbuf[w * 4608 + (mf * 16 + fh * 4 + j) * 72 + nf * 16 + fr] =
                    f2bf(acc[mf][nf][j]);
    const int o = (bo * 4 + w) * 64 + bn4 * 4 + wn;
    unsigned short* dst = Wt + (size_t)o * 4096;
#pragma unroll
    for (int i = 0; i < 8; ++i) {
        int c = i * 64 + lane;
        *(u16x8*)&dst[c * 8] =
            *(const u16x8*)&lbuf[w * 4608 + (c >> 3) * 72 + (c & 7) * 8];
    }
}

// ---------------------------------------------------------------------------
// Kernel 2: C = A * Wt^T.  v10 — A-in-registers, depth-2, spill-proofed:
//   R7 skeleton (64M x 128N, BK=64, 4 waves 2x2, wave 32x64, acc 2x4, grid
//   512 = 2 desync blocks/CU).  A-fragments global->VGPR (verified correct
//   in R10); B-only LDS: 3 bufs x 16KB = 48KB/block (2 blocks = 96 <= 160KB).
//   Fixes for R10's 2x regression:
//   (1) depth-2 prefetch on BOTH paths: 3 named A-reg sets P/Q/R (rule 20)
//       + 3 B bufs, VMCNT(16) = 2 phases x 8 ops in flight (never 0 in loop);
//       R10's depth-1 exposed ~500cyc latency per phase.
//   (2) amdgpu_waves_per_eu(2,2): R10's allocator chose VGPR=64 (< the ~110
//       live floor) and spilled every phase; pinning 2 waves/EU gives the
//       256-reg budget. Expect VGPR_Count 130-170 — that's the spill check.
//   B swizzle / XCD map / epilogue verbatim R7 (conflicts measured 0).
// ---------------------------------------------------------------------------
__global__ __launch_bounds__(256)
__attribute__((amdgpu_waves_per_eu(2, 2)))
void gemm_areg2(const unsigned short* __restrict__ A,
                const unsigned short* __restrict__ Bt,
                float* __restrict__ C) {
    constexpr int K = 4096;
    constexpr int N = 4096;
    constexpr int BK = 64;
    __shared__ alignas(16) char lds[3][16384];   // [buf][B 16KB]
    const int tid = threadIdx.x;
    const int lane = tid & 63, w = tid >> 6;
    const int wm = w >> 1, wn = w & 1;
    const int xcd = blockIdx.x & 7, r = blockIdx.x >> 3;  // r 0..63
    const int bn = xcd * 4 + (r & 3);            // 0..31
    const int bm = r >> 2;                       // 0..15

    // --- B staging: 1024 16B slots (4/thread), source-side XOR swizzle ---
    const unsigned short* gB[4];
    int lBoff[4];
#pragma unroll
    for (int i = 0; i < 4; ++i) {
        int cs = i * 256 + tid;
        int row = cs >> 3;
        int c = (cs & 7) ^ ((row >> 1) & 7);
        gB[i] = Bt + (size_t)(bn * 128 + row) * K + c * 8;
        lBoff[i] = i * 4096 + w * 1024;          // wave-uniform base (+lane*16 HW)
    }

#define STAGEB(buf, tt)                                            \
    do {                                                           \
        glds16(gB[0] + (tt) * BK, &lds[buf][lBoff[0]]);            \
        glds16(gB[1] + (tt) * BK, &lds[buf][lBoff[1]]);            \
        glds16(gB[2] + (tt) * BK, &lds[buf][lBoff[2]]);            \
        glds16(gB[3] + (tt) * BK, &lds[buf][lBoff[3]]);            \
    } while (0)

    // --- A fragment pointers (global, per-lane; verified in R10) ---
    const int fr = lane & 15, fh = lane >> 4;
    const unsigned short* a00 = A + (size_t)(bm * 64 + wm * 32 + fr) * K + fh * 8;
    const unsigned short* a01 = a00 + 32;               // kk=1
    const unsigned short* a10 = a00 + (size_t)16 * K;   // m=1
    const unsigned short* a11 = a10 + 32;

    bf16x8 aP00, aP01, aP10, aP11;               // 3 rotating A-reg sets
    bf16x8 aQ00, aQ01, aQ10, aQ11;
    bf16x8 aR00, aR01, aR10, aR11;
#define ALOAD(S, tt)                                               \
    do {                                                           \
        a##S##00 = *(const bf16x8*)(a00 + (tt) * BK);              \
        a##S##01 = *(const bf16x8*)(a01 + (tt) * BK);              \
        a##S##10 = *(const bf16x8*)(a10 + (tt) * BK);              \
        a##S##11 = *(const bf16x8*)(a11 + (tt) * BK);              \
    } while (0)

    // --- B fragment read offsets (swizzled) ---
    const int sk = (fr >> 1) & 7;
    const int boff0 = (wn * 64 + fr) * 128 + ((fh ^ sk) << 4);           // kk=0
    const int boff1 = (wn * 64 + fr) * 128 + (((4 + fh) ^ sk) << 4);     // kk=1

    f32x4 acc[2][4] = {};

#define CHALF(base, bof, A0, A1)                                   \
    do {                                                           \
        bf16x8 b0 = *(const bf16x8*)((base) + (bof));              \
        bf16x8 b1 = *(const bf16x8*)((base) + (bof) + 2048);       \
        bf16x8 b2 = *(const bf16x8*)((base) + (bof) + 4096);       \
        bf16x8 b3 = *(const bf16x8*)((base) + (bof) + 6144);       \
        acc[0][0] = MFMA16(A0, b0, acc[0][0]);                     \
        acc[0][1] = MFMA16(A0, b1, acc[0][1]);                     \
        acc[0][2] = MFMA16(A0, b2, acc[0][2]);                     \
        acc[0][3] = MFMA16(A0, b3, acc[0][3]);                     \
        acc[1][0] = MFMA16(A1, b0, acc[1][0]);                     \
        acc[1][1] = MFMA16(A1, b1, acc[1][1]);                     \
        acc[1][2] = MFMA16(A1, b2, acc[1][2]);                     \
        acc[1][3] = MFMA16(A1, b3, acc[1][3]);                     \
    } while (0)

#define COMPUTE(buf, S)                                            \
    do {                                                           \
        const char* base_ = &lds[buf][0];                          \
        CHALF(base_, boff0, a##S##00, a##S##10);                   \
        CHALF(base_, boff1, a##S##01, a##S##11);                   \
    } while (0)

    // phase p: A-set = p%3 (P,Q,R), B-buf = p%3; prefetch distance 2.
#define PHASE(p, Sp2, Bp2, Sc, Bc)                                 \
    do {                                                           \
        ALOAD(Sp2, (p) + 2);                                       \
        STAGEB(Bp2, (p) + 2);                                      \
        VMCNT(16);                                                 \
        BAR();                                                     \
        COMPUTE(Bc, Sc);                                           \
        BAR();                                                     \
    } while (0)

    // --- prologue: fill 2 phases ---
    ALOAD(P, 0); STAGEB(0, 0);
    ALOAD(Q, 1); STAGEB(1, 1);
    // --- main loop: phases 0..59 (20 iterations x 3) ---
    for (int t = 0; t < 60; t += 3) {
        PHASE(t,     R, 2, P, 0);
        PHASE(t + 1, P, 0, Q, 1);
        PHASE(t + 2, Q, 1, R, 2);
    }
    // --- epilogue: phases 60..63 ---
    PHASE(60, R, 2, P, 0);                       // prefetch 62
    PHASE(61, P, 0, Q, 1);                       // prefetch 63
    VMCNT(8);  BAR(); COMPUTE(2, R); BAR();      // phase 62
    VMCNT(0);  BAR(); COMPUTE(0, P);             // phase 63

    // --- epilogue: plain coalesced stores ---
    const int crow0 = bm * 64 + wm * 32 + fh * 4;
    const int ccol0 = bn * 128 + wn * 64 + fr;
#pragma unroll
    for (int m = 0; m < 2; ++m)
#pragma unroll
        for (int n = 0; n < 4; ++n)
#pragma unroll
            for (int j = 0; j < 4; ++j)
                C[(size_t)(crow0 + m * 16 + j) * N + (ccol0 + n * 16)] = acc[m][n][j];
#undef STAGEB
#undef ALOAD
#undef CHALF
#undef COMPUTE
#undef PHASE
}

// ---------------------------------------------------------------------------
extern "C" void kernel_launch(void* const* d_in, const int* in_sizes, int n_in,
                              void* d_out, int out_size, void* d_ws, size_t ws_size,
                              hipStream_t stream) {
    const float* inputs  = (const float*)d_in[0];   // [1024, 4096] f32
    const float* cores   = (const float*)d_in[1];   // [4, 16] f32
    const float* factors = (const float*)d_in[2];   // [4,4,8,8,2] f32
    float* out = (float*)d_out;                     // [1024, 4096] f32

    char* ws = (char*)d_ws;
    unsigned short* xb = (unsigned short*)ws;                       //  8 MB bf16 x
    unsigned short* Wt = (unsigned short*)(ws + (8u << 20));        // 32 MB bf16 W^T

    prep_fused<<<5120, 256, 0, stream>>>(factors, cores,
                                         (const float4*)inputs, (ushort4*)xb, Wt);
    gemm_areg2<<<512, 256, 0, stream>>>(xb, Wt, out);
}

// Round 12
// 69.549 us; speedup vs baseline: 1.5261x; 1.5261x over previous
//
#include <hip/hip_runtime.h>
#include <hip/hip_bf16.h>
#include <stdint.h>

typedef __attribute__((ext_vector_type(8))) __bf16 bf16x8;
typedef __attribute__((ext_vector_type(4))) float f32x4;
typedef __attribute__((ext_vector_type(8))) unsigned short u16x8;

__device__ __forceinline__ unsigned short f2bf(float f) {
    unsigned u = __builtin_bit_cast(unsigned, f);
    return (unsigned short)((u + 0x7fffu + ((u >> 16) & 1u)) >> 16);  // RNE
}

__device__ __forceinline__ void glds16(const void* g, void* l) {
    __builtin_amdgcn_global_load_lds(
        (const __attribute__((address_space(1))) unsigned int*)(uintptr_t)g,
        (__attribute__((address_space(3))) unsigned int*)l, 16, 0, 0);
}

#define VMCNT(n) asm volatile("s_waitcnt vmcnt(" #n ")" ::: "memory")
#define BAR()                                  \
    do {                                       \
        asm volatile("" ::: "memory");         \
        __builtin_amdgcn_s_barrier();          \
        asm volatile("" ::: "memory");         \
    } while (0)

#define MFMA16(a, b, c) __builtin_amdgcn_mfma_f32_16x16x32_bf16((a), (b), (c), 0, 0, 0)

// ---------------------------------------------------------------------------
// Kernel 1 (fused prep, VERIFIED R9): blocks [0,1024) build W; rest cvt x.
// ---------------------------------------------------------------------------
__global__ __launch_bounds__(256) void prep_fused(const float* __restrict__ factors,
                                                  const float* __restrict__ cores,
                                                  const float4* __restrict__ xin,
                                                  ushort4* __restrict__ xb,
                                                  unsigned short* __restrict__ Wt) {
    if (blockIdx.x >= 1024) {
        int i = (blockIdx.x - 1024) * 256 + threadIdx.x;
        float4 v = xin[i];
        ushort4 o;
        o.x = f2bf(v.x); o.y = f2bf(v.y); o.z = f2bf(v.z); o.w = f2bf(v.w);
        xb[i] = o;
        return;
    }
    __shared__ unsigned short As2[256 * 40];
    __shared__ unsigned short Bs2[64 * 40];
    __shared__ unsigned short lbuf[4 * 64 * 72];
    const int tid = threadIdx.x, lane = tid & 63, w = tid >> 6;
    const int bo = blockIdx.x >> 6, bn4 = (blockIdx.x >> 2) & 15, wn = blockIdx.x & 3;

    {
        int o01 = bo * 4 + (tid >> 6), a01 = tid & 63;
        int o0 = o01 >> 3, o1 = o01 & 7, a0 = a01 >> 3, a1 = a01 & 7;
#pragma unroll
        for (int k = 0; k < 16; ++k) {
            int b = k >> 2, q = k & 3, r0 = q >> 1, r1 = q & 1;
            float v = factors[b*512 +   0 + a0*16 + o0*2 + r0]
                    * factors[b*512 + 128 + a1*16 + o1*2 + r1];
            As2[tid * 40 + k] = f2bf(v);
            As2[tid * 40 + 16 + k] = 0;
        }
    }
    {
        int o23 = bn4 * 4 + wn, o2 = o23 >> 3, o3 = o23 & 7;
#pragma unroll
        for (int rep = 0; rep < 4; ++rep) {
            int task = rep * 256 + tid;
            int n = task >> 4, k = task & 15;
            int a2 = n >> 3, a3 = n & 7;
            int b = k >> 2, q = k & 3, r0 = q >> 1, r1 = q & 1;
            float s = 0.f;
#pragma unroll
            for (int r2 = 0; r2 < 2; ++r2)
#pragma unroll
                for (int r3 = 0; r3 < 2; ++r3)
                    s += factors[b*512 + 256 + a2*16 + o2*2 + r2]
                       * factors[b*512 + 384 + a3*16 + o3*2 + r3]
                       * cores[b*16 + r3*8 + r2*4 + r1*2 + r0];
            Bs2[n * 40 + k] = f2bf(s);
            Bs2[n * 40 + 16 + k] = 0;
        }
    }
    __syncthreads();

    const int fr = lane & 15, fh = lane >> 4;
    bf16x8 af[4], bf_[4];
#pragma unroll
    for (int mf = 0; mf < 4; ++mf)
        af[mf] = *(const bf16x8*)&As2[(w * 64 + mf * 16 + fr) * 40 + fh * 8];
#pragma unroll
    for (int nf = 0; nf < 4; ++nf)
        bf_[nf] = *(const bf16x8*)&Bs2[(nf * 16 + fr) * 40 + fh * 8];
    f32x4 acc[4][4] = {};
#pragma unroll
    for (int mf = 0; mf < 4; ++mf)
#pragma unroll
        for (int nf = 0; nf < 4; ++nf)
            acc[mf][nf] = MFMA16(af[mf], bf_[nf], acc[mf][nf]);
#pragma unroll
    for (int mf = 0; mf < 4; ++mf)
#pragma unroll
        for (int nf = 0; nf < 4; ++nf)
#pragma unroll
            for (int j = 0; j < 4; ++j)
                lbuf[w * 4608 + (mf * 16 + fh * 4 + j) * 72 + nf * 16 + fr] =
                    f2bf(acc[mf][nf][j]);
    const int o = (bo * 4 + w) * 64 + bn4 * 4 + wn;
    unsigned short* dst = Wt + (size_t)o * 4096;
#pragma unroll
    for (int i = 0; i < 8; ++i) {
        int c = i * 64 + lane;
        *(u16x8*)&dst[c * 8] =
            *(const u16x8*)&lbuf[w * 4608 + (c >> 3) * 72 + (c & 7) * 8];
    }
}

// ---------------------------------------------------------------------------
// Kernel 2: 8-phase 256^2 GEMM (m201-style port), split-K x4 -> partials.
//   BM=BN=256, BK=64, 512 thr = 8 waves (2M x 4N), wave-tile 128x64,
//   acc[8][4] f32x4.  LDS 128KB: A[2 bufs][256r][64c] + B same, bf16,
//   source-side XOR chunk swizzle (key (row>>1)&7; read XOR sk=(fr>>1)&7 —
//   scheme measured conflict-free R3-R7).
//   Per K-tile: 4 phases {ds_read frags; 2 glds (next tile); [vmcnt]; BAR;
//   setprio(1); 16 MFMA; setprio(0); BAR}.  Counted vmcnt(2) at ph0 & ph3
//   only — loads stay 2-8 outstanding, never drained in the loop.
//   glds pair order B0B1|B2B3|A0A2|A1A3 matches phase read needs:
//   ph0 reads B(kk0)+A rows {0-63,128-191}; ph1 A rows {64-127,192-255}.
//   Split-K x4: ks owns K-chunk of 1024 (16 tiles); grid 4*64=256 = 1/CU;
//   plain stores to private partial buffer (no atomics — R6 lesson).
// ---------------------------------------------------------------------------
__global__ __launch_bounds__(512, 2) void gemm_8ph(const unsigned short* __restrict__ A,
                                                   const unsigned short* __restrict__ Bt,
                                                   float* __restrict__ P) {
    constexpr int K = 4096;
    constexpr int N = 4096;
    constexpr int BK = 64;
    constexpr int KCH = 1024;
    __shared__ alignas(16) char lds[131072];     // A: [0,64K) 2 bufs; B: [64K,128K)
    const int tid = threadIdx.x, lane = tid & 63, wid = tid >> 6;
    const int wr = wid >> 2, wc = wid & 3;       // 2M x 4N
    const int ks = blockIdx.x >> 6;              // 0..3
    const int tile = blockIdx.x & 63;
    const int bm = tile >> 4, bn = tile & 15;

    // --- staging addresses: per tile A = 2048 16B slots (4/thread), B same ---
    const unsigned short* gA[4]; const unsigned short* gB[4];
#pragma unroll
    for (int i = 0; i < 4; ++i) {
        int cs = i * 512 + tid;
        int row = cs >> 3;                        // 0..255
        int c = (cs & 7) ^ ((row >> 1) & 7);      // source-side XOR swizzle
        gA[i] = A  + (size_t)(bm * 256 + row) * K + ks * KCH + c * 8;
        gB[i] = Bt + (size_t)(bn * 256 + row) * K + ks * KCH + c * 8;
    }
#define STG_A(i_, nbuf, kt) glds16(gA[i_] + (kt), lds + (nbuf) * 32768 + (i_) * 8192 + wid * 1024)
#define STG_B(i_, nbuf, kt) glds16(gB[i_] + (kt), lds + 65536 + (nbuf) * 32768 + (i_) * 8192 + wid * 1024)

    // --- fragment read offsets (swizzled) ---
    const int fr = lane & 15, fh = lane >> 4, sk = (fr >> 1) & 7;
    const int ck0 = ((0 + fh) ^ sk) << 4;         // kk=0 chunk byte offset
    const int ck1 = ((4 + fh) ^ sk) << 4;         // kk=1
    const int aRow = (wr * 128 + fr) * 128;       // + m*2048
    const int bRow = (wc * 64 + fr) * 128;        // + n*2048

#define DSA(cbuf, kkc, m) (*(const bf16x8*)(lds + (cbuf) * 32768 + aRow + (m) * 2048 + (kkc)))
#define DSB(cbuf, kkc, n) (*(const bf16x8*)(lds + 65536 + (cbuf) * 32768 + bRow + (n) * 2048 + (kkc)))

    f32x4 acc[8][4] = {};
    bf16x8 vb0, vb1, vb2, vb3;                    // current-kk B frags (live 2 phases)

#define MMROW(mi, a_)                                             \
    acc[mi][0] = MFMA16(a_, vb0, acc[mi][0]);                     \
    acc[mi][1] = MFMA16(a_, vb1, acc[mi][1]);                     \
    acc[mi][2] = MFMA16(a_, vb2, acc[mi][2]);                     \
    acc[mi][3] = MFMA16(a_, vb3, acc[mi][3]);

#define PH_BA(cbuf, kkc, S1, S2, W)  /* B(kk) + A m0-3 -> acc[0..3] */ \
    do {                                                          \
        bf16x8 a0, a1, a2, a3;                                    \
        vb0 = DSB(cbuf, kkc, 0); vb1 = DSB(cbuf, kkc, 1);         \
        vb2 = DSB(cbuf, kkc, 2); vb3 = DSB(cbuf, kkc, 3);         \
        a0 = DSA(cbuf, kkc, 0); a1 = DSA(cbuf, kkc, 1);           \
        a2 = DSA(cbuf, kkc, 2); a3 = DSA(cbuf, kkc, 3);           \
        S1; S2; W;                                                \
        BAR();                                                    \
        __builtin_amdgcn_s_setprio(1);                            \
        MMROW(0, a0) MMROW(1, a1) MMROW(2, a2) MMROW(3, a3)       \
        __builtin_amdgcn_s_setprio(0);                            \
        BAR();                                                    \
    } while (0)

#define PH_A(cbuf, kkc, S1, S2, W)   /* A m4-7 -> acc[4..7] */    \
    do {                                                          \
        bf16x8 a0, a1, a2, a3;                                    \
        a0 = DSA(cbuf, kkc, 4); a1 = DSA(cbuf, kkc, 5);           \
        a2 = DSA(cbuf, kkc, 6); a3 = DSA(cbuf, kkc, 7);           \
        S1; S2; W;                                                \
        BAR();                                                    \
        __builtin_amdgcn_s_setprio(1);                            \
        MMROW(4, a0) MMROW(5, a1) MMROW(6, a2) MMROW(7, a3)       \
        __builtin_amdgcn_s_setprio(0);                            \
        BAR();                                                    \
    } while (0)

#define TILE(cbuf, nbuf, kt)                                                  \
    do {                                                                      \
        PH_BA(cbuf, ck0, STG_B(0, nbuf, kt), STG_B(1, nbuf, kt), VMCNT(2));   \
        PH_A (cbuf, ck0, STG_B(2, nbuf, kt), STG_B(3, nbuf, kt), (void)0);    \
        PH_BA(cbuf, ck1, STG_A(0, nbuf, kt), STG_A(2, nbuf, kt), (void)0);    \
        PH_A (cbuf, ck1, STG_A(1, nbuf, kt), STG_A(3, nbuf, kt), VMCNT(2));   \
    } while (0)

#define TILE_LAST(cbuf)                                                       \
    do {                                                                      \
        PH_BA(cbuf, ck0, (void)0, (void)0, VMCNT(0));                         \
        PH_A (cbuf, ck0, (void)0, (void)0, (void)0);                          \
        PH_BA(cbuf, ck1, (void)0, (void)0, (void)0);                          \
        PH_A (cbuf, ck1, (void)0, (void)0, (void)0);                          \
    } while (0)

    // --- prologue: stage tile0 into buf0; newest 2 = (A1,A3) may stay in flight
    STG_B(0, 0, 0); STG_B(1, 0, 0); STG_B(2, 0, 0); STG_B(3, 0, 0);
    STG_A(0, 0, 0); STG_A(2, 0, 0); STG_A(1, 0, 0); STG_A(3, 0, 0);
    VMCNT(2);
    BAR();
    // --- main loop: 16 K-tiles ---
    for (int t = 0; t < 14; t += 2) {
        TILE(0, 1, (t + 1) * BK);
        TILE(1, 0, (t + 2) * BK);
    }
    TILE(0, 1, 15 * BK);
    TILE_LAST(1);

    // --- epilogue: plain stores to this ks's private partial buffer ---
    float* Po = P + (size_t)ks * 4194304;
    const int r0 = bm * 256 + wr * 128 + fh * 4;
    const int c0 = bn * 256 + wc * 64 + fr;
#pragma unroll
    for (int m = 0; m < 8; ++m)
#pragma unroll
        for (int n = 0; n < 4; ++n)
#pragma unroll
            for (int j = 0; j < 4; ++j)
                Po[(size_t)(r0 + m * 16 + j) * N + (c0 + n * 16)] = acc[m][n][j];
#undef STG_A
#undef STG_B
#undef DSA
#undef DSB
#undef MMROW
#undef PH_BA
#undef PH_A
#undef TILE
#undef TILE_LAST
}

// ---------------------------------------------------------------------------
// Kernel 3: C = P0 + P1 + P2 + P3 (streaming float4 reduce)
// ---------------------------------------------------------------------------
__global__ __launch_bounds__(256) void reduce4(const float4* __restrict__ P,
                                               float4* __restrict__ C) {
    int i = blockIdx.x * 256 + threadIdx.x;      // grid 4096 -> 1048576 float4
    float4 a = P[i];
    float4 b = P[i + 1048576];
    float4 c = P[i + 2097152];
    float4 d = P[i + 3145728];
    float4 o;
    o.x = (a.x + b.x) + (c.x + d.x);
    o.y = (a.y + b.y) + (c.y + d.y);
    o.z = (a.z + b.z) + (c.z + d.z);
    o.w = (a.w + b.w) + (c.w + d.w);
    C[i] = o;
}

// ---------------------------------------------------------------------------
extern "C" void kernel_launch(void* const* d_in, const int* in_sizes, int n_in,
                              void* d_out, int out_size, void* d_ws, size_t ws_size,
                              hipStream_t stream) {
    const float* inputs  = (const float*)d_in[0];   // [1024, 4096] f32
    const float* cores   = (const float*)d_in[1];   // [4, 16] f32
    const float* factors = (const float*)d_in[2];   // [4,4,8,8,2] f32
    float* out = (float*)d_out;                     // [1024, 4096] f32

    char* ws = (char*)d_ws;
    unsigned short* xb = (unsigned short*)ws;                       //  8 MB bf16 x
    unsigned short* Wt = (unsigned short*)(ws + (8u << 20));        // 32 MB bf16 W^T
    float* Pp = (float*)(ws + (40u << 20));                         // 64 MB partials

    prep_fused<<<5120, 256, 0, stream>>>(factors, cores,
                                         (const float4*)inputs, (ushort4*)xb, Wt);
    gemm_8ph<<<256, 512, 0, stream>>>(xb, Wt, Pp);
    reduce4<<<4096, 256, 0, stream>>>((const float4*)Pp, (float4*)out);
}

// Round 13
// 68.966 us; speedup vs baseline: 1.5390x; 1.0085x over previous
//
#include <hip/hip_runtime.h>
#include <hip/hip_bf16.h>
#include <stdint.h>

typedef __attribute__((ext_vector_type(8))) __bf16 bf16x8;
typedef __attribute__((ext_vector_type(4))) float f32x4;
typedef __attribute__((ext_vector_type(8))) unsigned short u16x8;

__device__ __forceinline__ unsigned short f2bf(float f) {
    unsigned u = __builtin_bit_cast(unsigned, f);
    return (unsigned short)((u + 0x7fffu + ((u >> 16) & 1u)) >> 16);  // RNE
}

__device__ __forceinline__ void glds16(const void* g, void* l) {
    __builtin_amdgcn_global_load_lds(
        (const __attribute__((address_space(1))) unsigned int*)(uintptr_t)g,
        (__attribute__((address_space(3))) unsigned int*)l, 16, 0, 0);
}

#define VMCNT(n) asm volatile("s_waitcnt vmcnt(" #n ")" ::: "memory")
#define BAR()                                  \
    do {                                       \
        asm volatile("" ::: "memory");         \
        __builtin_amdgcn_s_barrier();          \
        asm volatile("" ::: "memory");         \
    } while (0)

#define MFMA16(a, b, c) __builtin_amdgcn_mfma_f32_16x16x32_bf16((a), (b), (c), 0, 0, 0)

// ---------------------------------------------------------------------------
// Kernel 1 (fused prep, VERIFIED R9): blocks [0,1024) build W; rest cvt x.
// ---------------------------------------------------------------------------
__global__ __launch_bounds__(256) void prep_fused(const float* __restrict__ factors,
                                                  const float* __restrict__ cores,
                                                  const float4* __restrict__ xin,
                                                  ushort4* __restrict__ xb,
                                                  unsigned short* __restrict__ Wt) {
    if (blockIdx.x >= 1024) {
        int i = (blockIdx.x - 1024) * 256 + threadIdx.x;
        float4 v = xin[i];
        ushort4 o;
        o.x = f2bf(v.x); o.y = f2bf(v.y); o.z = f2bf(v.z); o.w = f2bf(v.w);
        xb[i] = o;
        return;
    }
    __shared__ unsigned short As2[256 * 40];
    __shared__ unsigned short Bs2[64 * 40];
    __shared__ unsigned short lbuf[4 * 64 * 72];
    const int tid = threadIdx.x, lane = tid & 63, w = tid >> 6;
    const int bo = blockIdx.x >> 6, bn4 = (blockIdx.x >> 2) & 15, wn = blockIdx.x & 3;

    {
        int o01 = bo * 4 + (tid >> 6), a01 = tid & 63;
        int o0 = o01 >> 3, o1 = o01 & 7, a0 = a01 >> 3, a1 = a01 & 7;
#pragma unroll
        for (int k = 0; k < 16; ++k) {
            int b = k >> 2, q = k & 3, r0 = q >> 1, r1 = q & 1;
            float v = factors[b*512 +   0 + a0*16 + o0*2 + r0]
                    * factors[b*512 + 128 + a1*16 + o1*2 + r1];
            As2[tid * 40 + k] = f2bf(v);
            As2[tid * 40 + 16 + k] = 0;
        }
    }
    {
        int o23 = bn4 * 4 + wn, o2 = o23 >> 3, o3 = o23 & 7;
#pragma unroll
        for (int rep = 0; rep < 4; ++rep) {
            int task = rep * 256 + tid;
            int n = task >> 4, k = task & 15;
            int a2 = n >> 3, a3 = n & 7;
            int b = k >> 2, q = k & 3, r0 = q >> 1, r1 = q & 1;
            float s = 0.f;
#pragma unroll
            for (int r2 = 0; r2 < 2; ++r2)
#pragma unroll
                for (int r3 = 0; r3 < 2; ++r3)
                    s += factors[b*512 + 256 + a2*16 + o2*2 + r2]
                       * factors[b*512 + 384 + a3*16 + o3*2 + r3]
                       * cores[b*16 + r3*8 + r2*4 + r1*2 + r0];
            Bs2[n * 40 + k] = f2bf(s);
            Bs2[n * 40 + 16 + k] = 0;
        }
    }
    __syncthreads();

    const int fr = lane & 15, fh = lane >> 4;
    bf16x8 af[4], bf_[4];
#pragma unroll
    for (int mf = 0; mf < 4; ++mf)
        af[mf] = *(const bf16x8*)&As2[(w * 64 + mf * 16 + fr) * 40 + fh * 8];
#pragma unroll
    for (int nf = 0; nf < 4; ++nf)
        bf_[nf] = *(const bf16x8*)&Bs2[(nf * 16 + fr) * 40 + fh * 8];
    f32x4 acc[4][4] = {};
#pragma unroll
    for (int mf = 0; mf < 4; ++mf)
#pragma unroll
        for (int nf = 0; nf < 4; ++nf)
            acc[mf][nf] = MFMA16(af[mf], bf_[nf], acc[mf][nf]);
#pragma unroll
    for (int mf = 0; mf < 4; ++mf)
#pragma unroll
        for (int nf = 0; nf < 4; ++nf)
#pragma unroll
            for (int j = 0; j < 4; ++j)
                lbuf[w * 4608 + (mf * 16 + fh * 4 + j) * 72 + nf * 16 + fr] =
                    f2bf(acc[mf][nf][j]);
    const int o = (bo * 4 + w) * 64 + bn4 * 4 + wn;
    unsigned short* dst = Wt + (size_t)o * 4096;
#pragma unroll
    for (int i = 0; i < 8; ++i) {
        int c = i * 64 + lane;
        *(u16x8*)&dst[c * 8] =
            *(const u16x8*)&lbuf[w * 4608 + (c >> 3) * 72 + (c & 7) * 8];
    }
}

// ---------------------------------------------------------------------------
// Kernel 2: partials += A * Wt^T.  v11 — R7 skeleton, 64x64 waves, split-K x2:
//   tile 128(M) x 128(N), BK=32, 4 waves (2x2), wave-tile 64x64, acc 4x4.
//   Rationale (R7 cost model, confirmed twice): gemm is LDS-throughput-bound
//   at ~85 B/cyc/CU effective; LDS-bytes/FLOP is set by wave-tile geometry
//   FLOP/B = MwNw/(Mw+Nw): 64x64 waves = 32 vs R7's 32x64 = 21.3 (-33%).
//   R5 had 64x64 waves but 1 block/CU (stall-bound); this keeps BOTH:
//   BK=32 -> 3 bufs x 16KB = 48KB/block -> 2 desync blocks/CU (grid 512 via
//   split-K x2, KCH=2048, 64 steps).  Depth-2 pipeline, counted VMCNT(8/4/0)
//   for 4 glds/stage (never 0 in loop) — verbatim R7 schedule shape.
//   Swizzle re-derived for 4-chunk (64B) rows: source c = p ^ ((row>>1)&3),
//   read chunk fh ^ ((fr>>1)&3); (row-parity, chunk) covers all 8 bank
//   quads, 2 lanes each = free.  Partials to private buffers (no atomics).
//   XCD map: xcd owns 4 bn (4MB W panel L2-resident, shared by both ks).
// ---------------------------------------------------------------------------
__global__ __launch_bounds__(256, 2) void gemm_128sk2(const unsigned short* __restrict__ A,
                                                      const unsigned short* __restrict__ Bt,
                                                      float* __restrict__ P) {
    constexpr int K = 4096;
    constexpr int N = 4096;
    constexpr int BK = 32;
    constexpr int KCH = 2048;                    // 64 steps per block
    __shared__ alignas(16) char lds[3][16384];   // [buf][A 8KB | B 8KB]
    const int tid = threadIdx.x;
    const int lane = tid & 63, w = tid >> 6;
    const int wm = w >> 1, wn = w & 1;           // 2x2 waves, wave-tile 64x64
    const int xcd = blockIdx.x & 7, r = blockIdx.x >> 3;  // r 0..63
    const int bn = xcd * 4 + (r & 3);            // 0..31
    const int bm = (r >> 2) & 7;                 // 0..7
    const int ks = r >> 5;                       // 0..1

    // --- staging: A = 512 16B slots (2/thread), B = 512 (2/thread) ---
    // slot cs: row = cs>>2 (4 chunks per 64B row), phys chunk p = cs&3,
    // fetched logical chunk c = p ^ ((row>>1)&3)
    const unsigned short* gA[2]; const unsigned short* gB[2];
    int lAoff[2], lBoff[2];
#pragma unroll
    for (int i = 0; i < 2; ++i) {
        int cs = i * 256 + tid;
        int row = cs >> 2;
        int c = (cs & 3) ^ ((row >> 1) & 3);
        gA[i] = A  + (size_t)(bm * 128 + row) * K + ks * KCH + c * 8;
        gB[i] = Bt + (size_t)(bn * 128 + row) * K + ks * KCH + c * 8;
        lAoff[i] = i * 4096 + w * 1024;          // wave-uniform base (+lane*16 HW)
        lBoff[i] = 8192 + i * 4096 + w * 1024;
    }

#define STAGE(buf, tt)                                             \
    do {                                                           \
        glds16(gA[0] + (tt) * BK, &lds[buf][lAoff[0]]);            \
        glds16(gA[1] + (tt) * BK, &lds[buf][lAoff[1]]);            \
        glds16(gB[0] + (tt) * BK, &lds[buf][lBoff[0]]);            \
        glds16(gB[1] + (tt) * BK, &lds[buf][lBoff[1]]);            \
    } while (0)

    // --- fragment read offsets (swizzled): chunk = fh ^ ((fr>>1)&3) ---
    const int fr = lane & 15, fh = lane >> 4;
    const int xoff = (fh ^ ((fr >> 1) & 3)) << 4;
    int aoff[4], boff[4];
#pragma unroll
    for (int m = 0; m < 4; ++m) aoff[m] = (wm * 64 + m * 16 + fr) * 64 + xoff;
#pragma unroll
    for (int n = 0; n < 4; ++n) boff[n] = 8192 + (wn * 64 + n * 16 + fr) * 64 + xoff;

    f32x4 acc[4][4] = {};

#define COMPUTE(buf)                                                          \
    do {                                                                      \
        const char* base = &lds[buf][0];                                      \
        bf16x8 af[4], bf[4];                                                  \
        _Pragma("unroll")                                                     \
        for (int m = 0; m < 4; ++m) af[m] = *(const bf16x8*)(base + aoff[m]); \
        _Pragma("unroll")                                                     \
        for (int n = 0; n < 4; ++n) bf[n] = *(const bf16x8*)(base + boff[n]); \
        _Pragma("unroll")                                                     \
        for (int m = 0; m < 4; ++m)                                           \
            _Pragma("unroll")                                                 \
            for (int n = 0; n < 4; ++n)                                       \
                acc[m][n] = MFMA16(af[m], bf[n], acc[m][n]);                  \
    } while (0)

#define PHASE(tb, sbuf, cbuf)                                                 \
    do {                                                                      \
        STAGE(sbuf, (tb) + 2);                                                \
        VMCNT(8);                                                             \
        BAR();                                                                \
        COMPUTE(cbuf);                                                        \
        BAR();                                                                \
    } while (0)

    // --- depth-2 pipelined main loop: 64 steps (STAGE(s) targets buf s%3) ---
    STAGE(0, 0);
    STAGE(1, 1);
    for (int t = 0; t < 60; t += 3) {            // phases 0..59
        PHASE(t, 2, 0);
        PHASE(t + 1, 0, 1);
        PHASE(t + 2, 1, 2);
    }
    PHASE(60, 2, 0);                             // stage 62, compute 60
    PHASE(61, 0, 1);                             // stage 63, compute 61
    VMCNT(4);  BAR(); COMPUTE(2); BAR();         // compute 62
    VMCNT(0);  BAR(); COMPUTE(0);                // compute 63

    // --- epilogue: plain stores to this ks's private partial buffer ---
    float* Po = P + (size_t)ks * 4194304;
    const int crow0 = bm * 128 + wm * 64 + fh * 4;
    const int ccol0 = bn * 128 + wn * 64 + fr;
#pragma unroll
    for (int m = 0; m < 4; ++m)
#pragma unroll
        for (int n = 0; n < 4; ++n)
#pragma unroll
            for (int j = 0; j < 4; ++j)
                Po[(size_t)(crow0 + m * 16 + j) * N + (ccol0 + n * 16)] = acc[m][n][j];
#undef STAGE
#undef COMPUTE
#undef PHASE
}

// ---------------------------------------------------------------------------
// Kernel 3: C = P0 + P1 (streaming float4 reduce)
// ---------------------------------------------------------------------------
__global__ __launch_bounds__(256) void reduce2(const float4* __restrict__ P,
                                               float4* __restrict__ C) {
    int i = blockIdx.x * 256 + threadIdx.x;      // grid 4096 -> 1048576 float4
    float4 a = P[i];
    float4 b = P[i + 1048576];
    float4 o;
    o.x = a.x + b.x;
    o.y = a.y + b.y;
    o.z = a.z + b.z;
    o.w = a.w + b.w;
    C[i] = o;
}

// ---------------------------------------------------------------------------
extern "C" void kernel_launch(void* const* d_in, const int* in_sizes, int n_in,
                              void* d_out, int out_size, void* d_ws, size_t ws_size,
                              hipStream_t stream) {
    const float* inputs  = (const float*)d_in[0];   // [1024, 4096] f32
    const float* cores   = (const float*)d_in[1];   // [4, 16] f32
    const float* factors = (const float*)d_in[2];   // [4,4,8,8,2] f32
    float* out = (float*)d_out;                     // [1024, 4096] f32

    char* ws = (char*)d_ws;
    unsigned short* xb = (unsigned short*)ws;                       //  8 MB bf16 x
    unsigned short* Wt = (unsigned short*)(ws + (8u << 20));        // 32 MB bf16 W^T
    float* Pp = (float*)(ws + (40u << 20));                         // 32 MB partials

    prep_fused<<<5120, 256, 0, stream>>>(factors, cores,
                                         (const float4*)inputs, (ushort4*)xb, Wt);
    gemm_128sk2<<<512, 256, 0, stream>>>(xb, Wt, Pp);
    reduce2<<<4096, 256, 0, stream>>>((const float4*)Pp, (float4*)out);
}